// Round 5
// baseline (273.925 us; speedup 1.0000x reference)
//
#include <hip/hip_runtime.h>
#include <math.h>
#include <stdint.h>

#define NI 100000   // N_ITEMS
#define NB 512      // batch
#define NH 256      // hidden H
#define H3 768      // 3*H

typedef _Float16 f16x8 __attribute__((ext_vector_type(8)));
typedef float    f32x4 __attribute__((ext_vector_type(4)));

__device__ __forceinline__ float tanh_fast(float x) {
    x = fminf(fmaxf(x, -9.0f), 9.0f);
    const float e = __expf(2.0f * x);
    return (e - 1.0f) * __builtin_amdgcn_rcpf(e + 1.0f);
}

// ---------------- GRU gate elementwise (layer 0: gather x_proj inline) ----------------
__global__ void k_gates0(const int* __restrict__ idx,
                         const float* __restrict__ Wih0,   // (768, NI)
                         const float* __restrict__ bih0,   // (768)
                         const float* __restrict__ hp,     // (512,768)
                         const float* __restrict__ hprev,  // (512,256)
                         float* __restrict__ hnew)         // (512,256)
{
    const int b = blockIdx.x;
    const int j = threadIdx.x;          // 0..255
    const int ib = idx[b];
    const float xr = Wih0[(size_t)(j          ) * NI + ib] + bih0[j];
    const float xz = Wih0[(size_t)(j + NH     ) * NI + ib] + bih0[j + NH];
    const float xn = Wih0[(size_t)(j + 2 * NH ) * NI + ib] + bih0[j + 2 * NH];
    const float hr = hp[b * H3 + j];
    const float hz = hp[b * H3 + NH + j];
    const float hn = hp[b * H3 + 2 * NH + j];
    const float h  = hprev[b * NH + j];
    const float r = 1.0f / (1.0f + expf(-(xr + hr)));
    const float z = 1.0f / (1.0f + expf(-(xz + hz)));
    const float n = tanhf(xn + r * hn);
    hnew[b * NH + j] = (1.0f - z) * n + z * h;
}

// ---------------- GRU gate elementwise (layer 1) ----------------
__global__ void k_gates(const float* __restrict__ xp,
                        const float* __restrict__ hp,
                        const float* __restrict__ hprev,
                        float* __restrict__ hnew)
{
    const int b = blockIdx.x;
    const int j = threadIdx.x;
    const float xr = xp[b * H3 + j];
    const float xz = xp[b * H3 + NH + j];
    const float xn = xp[b * H3 + 2 * NH + j];
    const float hr = hp[b * H3 + j];
    const float hz = hp[b * H3 + NH + j];
    const float hn = hp[b * H3 + 2 * NH + j];
    const float h  = hprev[b * NH + j];
    const float r = 1.0f / (1.0f + expf(-(xr + hr)));
    const float z = 1.0f / (1.0f + expf(-(xz + hz)));
    const float n = tanhf(xn + r * hn);
    hnew[b * NH + j] = (1.0f - z) * n + z * h;
}

// ---------------- layer 2 gates: also emit fp16 copy of h2 for the MFMA GEMM --------
__global__ void k_gates_last(const float* __restrict__ xp,
                             const float* __restrict__ hp,
                             const float* __restrict__ hprev,
                             float* __restrict__ hnew,
                             _Float16* __restrict__ Xh)    // (512,256) fp16
{
    const int b = blockIdx.x;
    const int j = threadIdx.x;
    const float xr = xp[b * H3 + j];
    const float xz = xp[b * H3 + NH + j];
    const float xn = xp[b * H3 + 2 * NH + j];
    const float hr = hp[b * H3 + j];
    const float hz = hp[b * H3 + NH + j];
    const float hn = hp[b * H3 + 2 * NH + j];
    const float h  = hprev[b * NH + j];
    const float r = 1.0f / (1.0f + expf(-(xr + hr)));
    const float z = 1.0f / (1.0f + expf(-(xz + hz)));
    const float n = tanhf(xn + r * hn);
    const float v = (1.0f - z) * n + z * h;
    hnew[b * NH + j] = v;
    Xh[b * NH + j] = (_Float16)v;
}

// ---------------- small tiled fp32 GEMM:  C = A @ B.T + bias (z-batched) ----------------
__global__ __launch_bounds__(256)
void k_gemm_small(const float* __restrict__ A0,
                  const float* __restrict__ B0,
                  const float* __restrict__ bias0,
                  float* __restrict__ C0,
                  int M, int N, int K,
                  int sA, int sB, int sBias, int sC)
{
    constexpr int BM = 64, BN = 64, BK = 32;
    __shared__ float As[BK][BM];
    __shared__ float Bs[BK][BN];

    const float* A    = A0 + (size_t)blockIdx.z * sA;
    const float* Bm   = B0 + (size_t)blockIdx.z * sB;
    const float* bias = bias0 + (size_t)blockIdx.z * sBias;
    float*       C    = C0 + (size_t)blockIdx.z * sC;

    const int tid = threadIdx.x;
    const int tx  = tid & 15;
    const int ty  = tid >> 4;
    const int m0  = blockIdx.x * BM;
    const int n0  = blockIdx.y * BN;

    float acc[4][4];
#pragma unroll
    for (int i = 0; i < 4; i++)
#pragma unroll
        for (int j = 0; j < 4; j++) acc[i][j] = 0.0f;

    for (int k0 = 0; k0 < K; k0 += BK) {
#pragma unroll
        for (int f = 0; f < 2; f++) {
            const int fid = tid + f * 256;
            const int row = fid >> 3;
            const int t4  = fid & 7;
            const int mp  = row ^ ((t4 & 3) << 3);
            {
                const float4 v = *(const float4*)(A + (size_t)(m0 + row) * K + k0 + t4 * 4);
                As[t4 * 4 + 0][mp] = v.x; As[t4 * 4 + 1][mp] = v.y;
                As[t4 * 4 + 2][mp] = v.z; As[t4 * 4 + 3][mp] = v.w;
            }
            {
                const float4 v = *(const float4*)(Bm + (size_t)(n0 + row) * K + k0 + t4 * 4);
                Bs[t4 * 4 + 0][mp] = v.x; Bs[t4 * 4 + 1][mp] = v.y;
                Bs[t4 * 4 + 2][mp] = v.z; Bs[t4 * 4 + 3][mp] = v.w;
            }
        }
        __syncthreads();
#pragma unroll
        for (int kk = 0; kk < BK; kk++) {
            const int s = ((kk >> 2) & 3) << 3;
            const float4 a0 = *(const float4*)&As[kk][(ty * 4) ^ s];
            const float4 b0 = *(const float4*)&Bs[kk][(tx * 4) ^ s];
            const float av[4] = {a0.x, a0.y, a0.z, a0.w};
            const float bv[4] = {b0.x, b0.y, b0.z, b0.w};
#pragma unroll
            for (int i = 0; i < 4; i++)
#pragma unroll
                for (int j = 0; j < 4; j++)
                    acc[i][j] = fmaf(av[i], bv[j], acc[i][j]);
        }
        __syncthreads();
    }

#pragma unroll
    for (int i = 0; i < 4; i++) {
        const size_t rowoff = (size_t)(m0 + ty * 4 + i) * N;
        const int gn = n0 + tx * 4;
        const float4 bb = *(const float4*)(bias + gn);
        float4 v;
        v.x = acc[i][0] + bb.x; v.y = acc[i][1] + bb.y;
        v.z = acc[i][2] + bb.z; v.w = acc[i][3] + bb.w;
        *(float4*)(C + rowoff + gn) = v;
    }
}

// ---------------- output projection: act = tanh(x @ Wout.T + bout), fp16 MFMA ----------
// Streaming design: NO LDS, NO barriers in the K-loop. W rows have zero intra-block
// reuse, so each lane loads its MFMA W-fragment directly (8 contiguous fp32 = 2x
// dwordx4; a 16-lane group covers 16 rows x 64B — fully coalesced 64B lines), with
// depth-1 register prefetch (issue step t+1 W-loads before step t's MFMAs). X is fp16,
// 256 KB, L2/L1-hot, loaded per step. Latency hidden by prefetch + 3 blocks/CU
// (12 waves). mfma(A=W-frag, B=X-frag): D col(lane&15)=m, row((lane>>4)*4+r)=n ->
// per-lane float4 stores of 4 consecutive n. Math identical to round-3/4 (verified).
__global__ __launch_bounds__(256, 3)
void k_out_mfma(const _Float16* __restrict__ Xh,  // (512,256) fp16
                const float* __restrict__ W,      // (NI,256) fp32
                const float* __restrict__ bout,   // (NI)
                float* __restrict__ C)            // (512,NI)
{
    // bijective chunked XCD swizzle: nwg = 3128 = 8*391 exactly (m204)
    const int bid = blockIdx.x;
    const int wg  = (bid & 7) * 391 + (bid >> 3);
    const int my  = wg & 3;        // M-tile 0..3 (4 blocks sharing a W panel stay on one XCD)
    const int ny  = wg >> 2;       // N-tile 0..781

    const int n0   = ny * 128;
    const int tid  = threadIdx.x;
    const int lane = tid & 63;
    const int w    = tid >> 6;          // wave 0..3
    const int lr   = lane & 15;
    const int lg   = lane >> 4;         // 0..3
    const int wm   = w >> 1;            // 0..1 (M half)
    const int wn   = w & 1;             // 0..1 (N half)
    const int m0w  = my * 128 + wm * 64;

    // per-lane stream pointers (rows clamped; last N-tile has 96 OOB rows -> masked in epilogue)
    const float* wptr[4];
#pragma unroll
    for (int nf = 0; nf < 4; ++nf) {
        int gr = n0 + wn * 64 + nf * 16 + lr;
        if (gr >= NI) gr = NI - 1;
        wptr[nf] = W + (size_t)gr * NH + lg * 8;
    }
    const _Float16* xptr[4];
#pragma unroll
    for (int mf = 0; mf < 4; ++mf)
        xptr[mf] = Xh + (size_t)(m0w + mf * 16 + lr) * NH + lg * 8;

    f32x4 acc[4][4];
#pragma unroll
    for (int nf = 0; nf < 4; ++nf)
#pragma unroll
        for (int mf = 0; mf < 4; ++mf) acc[nf][mf] = (f32x4){0.f, 0.f, 0.f, 0.f};

    float4 wA[4][2], wB[4][2];
    f16x8  xf[4];

    // prologue: step-0 W
#pragma unroll
    for (int nf = 0; nf < 4; ++nf) {
        wA[nf][0] = *(const float4*)(wptr[nf]);
        wA[nf][1] = *(const float4*)(wptr[nf] + 4);
    }

#define OUT_STEP(CUR, NXT, T)                                                   \
    {                                                                           \
        if ((T) < 7) {                                                          \
            _Pragma("unroll")                                                   \
            for (int nf = 0; nf < 4; ++nf) {                                    \
                w##NXT[nf][0] = *(const float4*)(wptr[nf] + ((T) + 1) * 32);    \
                w##NXT[nf][1] = *(const float4*)(wptr[nf] + ((T) + 1) * 32 + 4);\
            }                                                                   \
        }                                                                       \
        _Pragma("unroll")                                                       \
        for (int mf = 0; mf < 4; ++mf)                                          \
            xf[mf] = *(const f16x8*)(xptr[mf] + (T) * 32);                      \
        _Pragma("unroll")                                                       \
        for (int nf = 0; nf < 4; ++nf) {                                        \
            f16x8 h;                                                            \
            h[0] = (_Float16)w##CUR[nf][0].x; h[1] = (_Float16)w##CUR[nf][0].y; \
            h[2] = (_Float16)w##CUR[nf][0].z; h[3] = (_Float16)w##CUR[nf][0].w; \
            h[4] = (_Float16)w##CUR[nf][1].x; h[5] = (_Float16)w##CUR[nf][1].y; \
            h[6] = (_Float16)w##CUR[nf][1].z; h[7] = (_Float16)w##CUR[nf][1].w; \
            _Pragma("unroll")                                                   \
            for (int mf = 0; mf < 4; ++mf)                                      \
                acc[nf][mf] = __builtin_amdgcn_mfma_f32_16x16x32_f16(           \
                    h, xf[mf], acc[nf][mf], 0, 0, 0);                           \
        }                                                                       \
    }

    OUT_STEP(A, B, 0)
    OUT_STEP(B, A, 1)
    OUT_STEP(A, B, 2)
    OUT_STEP(B, A, 3)
    OUT_STEP(A, B, 4)
    OUT_STEP(B, A, 5)
    OUT_STEP(A, B, 6)
    OUT_STEP(B, A, 7)
#undef OUT_STEP

    // epilogue: bias + tanh, per-lane float4 of 4 consecutive n
#pragma unroll
    for (int nf = 0; nf < 4; ++nf) {
        const int nb = n0 + wn * 64 + nf * 16;   // NI%16==0 -> frag all-in or all-out
        if (nb < NI) {
            const float4 bb = *(const float4*)(bout + nb + lg * 4);
#pragma unroll
            for (int mf = 0; mf < 4; ++mf) {
                const int m = m0w + mf * 16 + lr;
                float4 v;
                v.x = tanh_fast(acc[nf][mf][0] + bb.x);
                v.y = tanh_fast(acc[nf][mf][1] + bb.y);
                v.z = tanh_fast(acc[nf][mf][2] + bb.z);
                v.w = tanh_fast(acc[nf][mf][3] + bb.w);
                *(float4*)(C + (size_t)m * NI + nb + lg * 4) = v;
            }
        }
    }
}

extern "C" void kernel_launch(void* const* d_in, const int* in_sizes, int n_in,
                              void* d_out, int out_size, void* d_ws, size_t ws_size,
                              hipStream_t stream)
{
    const int*   idx    = (const int*)  d_in[0];
    const float* hidden = (const float*)d_in[1];   // (3,512,256)
    const float* Wih0   = (const float*)d_in[2];   // (768,100000)
    const float* WihHi  = (const float*)d_in[3];   // (2,768,256)
    const float* Whh    = (const float*)d_in[4];   // (3,768,256)
    const float* bih    = (const float*)d_in[5];   // (3,768)
    const float* bhh    = (const float*)d_in[6];   // (3,768)
    const float* Wout   = (const float*)d_in[7];   // (100000,256)
    const float* bout   = (const float*)d_in[8];   // (100000)

    float* act  = (float*)d_out;                  // (512, NI)
    float* hnew = act + (size_t)NB * NI;          // (3,512,256)
    // fp32 scratch lives in the activation region; final GEMM overwrites it.
    float* hp = act;                              // (3,512,768)
    float* xp = act + 3 * NB * H3;                // (512,768)
    // fp16 X lives in d_ws (must survive while the big GEMM writes act)
    _Float16* Xh = (_Float16*)d_ws;               // (512,256) = 256 KB

    const dim3 bs(256);
    const dim3 gs_hp(NB / 64, H3 / 64, 3);
    const dim3 gs_xp(NB / 64, H3 / 64, 1);

    // ---- all hidden-projections (depend only on input `hidden`) ----
    k_gemm_small<<<gs_hp, bs, 0, stream>>>(hidden, Whh, bhh, hp,
                                           NB, H3, NH, NB * NH, H3 * NH, H3, NB * H3);
    // ---- layer 0 (x_proj gathered inline) ----
    k_gates0<<<NB, bs, 0, stream>>>(idx, Wih0, bih, hp, hidden, hnew);
    // ---- layer 1 ----
    k_gemm_small<<<gs_xp, bs, 0, stream>>>(hnew, WihHi, bih + H3, xp,
                                           NB, H3, NH, 0, 0, 0, 0);
    k_gates<<<NB, bs, 0, stream>>>(xp, hp + NB * H3, hidden + NB * NH, hnew + NB * NH);
    // ---- layer 2 (also emits fp16 h2) ----
    k_gemm_small<<<gs_xp, bs, 0, stream>>>(hnew + NB * NH, WihHi + H3 * NH, bih + 2 * H3, xp,
                                           NB, H3, NH, 0, 0, 0, 0);
    k_gates_last<<<NB, bs, 0, stream>>>(xp, hp + 2 * NB * H3, hidden + 2 * NB * NH,
                                        hnew + 2 * NB * NH, Xh);

    // ---- output projection: 782 N-tiles x 4 M-tiles = 3128 blocks ----
    k_out_mfma<<<dim3(3128), dim3(256), 0, stream>>>(Xh, Wout, bout, act);
}

// Round 6
// 199.834 us; speedup vs baseline: 1.3708x; 1.3708x over previous
//
#include <hip/hip_runtime.h>
#include <math.h>
#include <stdint.h>

#define NI 100000   // N_ITEMS
#define NB 512      // batch
#define NH 256      // hidden H
#define H3 768      // 3*H

typedef _Float16 f16x8 __attribute__((ext_vector_type(8)));
typedef float    f32x4 __attribute__((ext_vector_type(4)));

__device__ __forceinline__ float tanh_fast(float x) {
    x = fminf(fmaxf(x, -9.0f), 9.0f);
    const float e = __expf(2.0f * x);
    return (e - 1.0f) * __builtin_amdgcn_rcpf(e + 1.0f);
}

// ---------------- GRU gate elementwise (layer 0: gather x_proj inline) ----------------
__global__ void k_gates0(const int* __restrict__ idx,
                         const float* __restrict__ Wih0,   // (768, NI)
                         const float* __restrict__ bih0,   // (768)
                         const float* __restrict__ hp,     // (512,768)
                         const float* __restrict__ hprev,  // (512,256)
                         float* __restrict__ hnew)         // (512,256)
{
    const int b = blockIdx.x;
    const int j = threadIdx.x;          // 0..255
    const int ib = idx[b];
    const float xr = Wih0[(size_t)(j          ) * NI + ib] + bih0[j];
    const float xz = Wih0[(size_t)(j + NH     ) * NI + ib] + bih0[j + NH];
    const float xn = Wih0[(size_t)(j + 2 * NH ) * NI + ib] + bih0[j + 2 * NH];
    const float hr = hp[b * H3 + j];
    const float hz = hp[b * H3 + NH + j];
    const float hn = hp[b * H3 + 2 * NH + j];
    const float h  = hprev[b * NH + j];
    const float r = 1.0f / (1.0f + expf(-(xr + hr)));
    const float z = 1.0f / (1.0f + expf(-(xz + hz)));
    const float n = tanhf(xn + r * hn);
    hnew[b * NH + j] = (1.0f - z) * n + z * h;
}

// ---------------- GRU gate elementwise (layer 1) ----------------
__global__ void k_gates(const float* __restrict__ xp,
                        const float* __restrict__ hp,
                        const float* __restrict__ hprev,
                        float* __restrict__ hnew)
{
    const int b = blockIdx.x;
    const int j = threadIdx.x;
    const float xr = xp[b * H3 + j];
    const float xz = xp[b * H3 + NH + j];
    const float xn = xp[b * H3 + 2 * NH + j];
    const float hr = hp[b * H3 + j];
    const float hz = hp[b * H3 + NH + j];
    const float hn = hp[b * H3 + 2 * NH + j];
    const float h  = hprev[b * NH + j];
    const float r = 1.0f / (1.0f + expf(-(xr + hr)));
    const float z = 1.0f / (1.0f + expf(-(xz + hz)));
    const float n = tanhf(xn + r * hn);
    hnew[b * NH + j] = (1.0f - z) * n + z * h;
}

// ---------------- layer 2 gates: also emit fp16 copy of h2 for the MFMA GEMM --------
__global__ void k_gates_last(const float* __restrict__ xp,
                             const float* __restrict__ hp,
                             const float* __restrict__ hprev,
                             float* __restrict__ hnew,
                             _Float16* __restrict__ Xh)    // (512,256) fp16
{
    const int b = blockIdx.x;
    const int j = threadIdx.x;
    const float xr = xp[b * H3 + j];
    const float xz = xp[b * H3 + NH + j];
    const float xn = xp[b * H3 + 2 * NH + j];
    const float hr = hp[b * H3 + j];
    const float hz = hp[b * H3 + NH + j];
    const float hn = hp[b * H3 + 2 * NH + j];
    const float h  = hprev[b * NH + j];
    const float r = 1.0f / (1.0f + expf(-(xr + hr)));
    const float z = 1.0f / (1.0f + expf(-(xz + hz)));
    const float n = tanhf(xn + r * hn);
    const float v = (1.0f - z) * n + z * h;
    hnew[b * NH + j] = v;
    Xh[b * NH + j] = (_Float16)v;
}

// ---------------- small tiled fp32 GEMM:  C = A @ B.T + bias (z-batched) ----------------
__global__ __launch_bounds__(256)
void k_gemm_small(const float* __restrict__ A0,
                  const float* __restrict__ B0,
                  const float* __restrict__ bias0,
                  float* __restrict__ C0,
                  int M, int N, int K,
                  int sA, int sB, int sBias, int sC)
{
    constexpr int BM = 64, BN = 64, BK = 32;
    __shared__ float As[BK][BM];
    __shared__ float Bs[BK][BN];

    const float* A    = A0 + (size_t)blockIdx.z * sA;
    const float* Bm   = B0 + (size_t)blockIdx.z * sB;
    const float* bias = bias0 + (size_t)blockIdx.z * sBias;
    float*       C    = C0 + (size_t)blockIdx.z * sC;

    const int tid = threadIdx.x;
    const int tx  = tid & 15;
    const int ty  = tid >> 4;
    const int m0  = blockIdx.x * BM;
    const int n0  = blockIdx.y * BN;

    float acc[4][4];
#pragma unroll
    for (int i = 0; i < 4; i++)
#pragma unroll
        for (int j = 0; j < 4; j++) acc[i][j] = 0.0f;

    for (int k0 = 0; k0 < K; k0 += BK) {
#pragma unroll
        for (int f = 0; f < 2; f++) {
            const int fid = tid + f * 256;
            const int row = fid >> 3;
            const int t4  = fid & 7;
            const int mp  = row ^ ((t4 & 3) << 3);
            {
                const float4 v = *(const float4*)(A + (size_t)(m0 + row) * K + k0 + t4 * 4);
                As[t4 * 4 + 0][mp] = v.x; As[t4 * 4 + 1][mp] = v.y;
                As[t4 * 4 + 2][mp] = v.z; As[t4 * 4 + 3][mp] = v.w;
            }
            {
                const float4 v = *(const float4*)(Bm + (size_t)(n0 + row) * K + k0 + t4 * 4);
                Bs[t4 * 4 + 0][mp] = v.x; Bs[t4 * 4 + 1][mp] = v.y;
                Bs[t4 * 4 + 2][mp] = v.z; Bs[t4 * 4 + 3][mp] = v.w;
            }
        }
        __syncthreads();
#pragma unroll
        for (int kk = 0; kk < BK; kk++) {
            const int s = ((kk >> 2) & 3) << 3;
            const float4 a0 = *(const float4*)&As[kk][(ty * 4) ^ s];
            const float4 b0 = *(const float4*)&Bs[kk][(tx * 4) ^ s];
            const float av[4] = {a0.x, a0.y, a0.z, a0.w};
            const float bv[4] = {b0.x, b0.y, b0.z, b0.w};
#pragma unroll
            for (int i = 0; i < 4; i++)
#pragma unroll
                for (int j = 0; j < 4; j++)
                    acc[i][j] = fmaf(av[i], bv[j], acc[i][j]);
        }
        __syncthreads();
    }

#pragma unroll
    for (int i = 0; i < 4; i++) {
        const size_t rowoff = (size_t)(m0 + ty * 4 + i) * N;
        const int gn = n0 + tx * 4;
        const float4 bb = *(const float4*)(bias + gn);
        float4 v;
        v.x = acc[i][0] + bb.x; v.y = acc[i][1] + bb.y;
        v.z = acc[i][2] + bb.z; v.w = acc[i][3] + bb.w;
        *(float4*)(C + rowoff + gn) = v;
    }
}

// ---------------- W pre-pass: fp32 -> fp16, 16B-chunk XOR swizzle baked into layout ----
// Wh[n][phys chunk p] holds logical chunk c = p ^ (n&7) of row n (chunk = 8 fp16 = 16B).
// GEMM then stages Wh linearly via global_load_lds (1KB-contiguous runs) and reads
// fragments with the same XOR -> bank-conflict-free (both-sides rule).
__global__ __launch_bounds__(256)
void k_wcvt(const float* __restrict__ W,        // (NI,256) fp32
            _Float16* __restrict__ Wh)          // (NI,256) fp16, swizzled
{
    const int t = blockIdx.x * 256 + threadIdx.x;   // chunk id
    if (t >= NI * 32) return;
    const int n = t >> 5;
    const int p = t & 31;
    const int c = p ^ (n & 7);
    const float* src = W + (size_t)n * NH + c * 8;
    const float4 a0 = *(const float4*)src;
    const float4 a1 = *(const float4*)(src + 4);
    f16x8 h;
    h[0] = (_Float16)a0.x; h[1] = (_Float16)a0.y;
    h[2] = (_Float16)a0.z; h[3] = (_Float16)a0.w;
    h[4] = (_Float16)a1.x; h[5] = (_Float16)a1.y;
    h[6] = (_Float16)a1.z; h[7] = (_Float16)a1.w;
    *(f16x8*)(Wh + (size_t)n * NH + p * 8) = h;     // linear 16B stores, coalesced
}

// ---------------- output projection: act = tanh(x @ Wout.T + bout), fp16 MFMA ----------
// 256 thr (4 waves, 2M x 2N), tile BM=128 x BN=128, FULL K=256 resident in LDS.
// Phase 1: stage entire 128-row W panel (fp16, pre-swizzled by k_wcvt) via
//          global_load_lds in 1KB-contiguous runs; ONE barrier.
// Phase 2: 8 MFMA k-steps purely from LDS (ds_read_b128, XOR chunk swizzle, ~2-way)
//          + X frags direct from L2. NO barriers, NO global W traffic.
// Phase 3: epilogue through LDS (reuse W buffer as fp32 C tile): fragments -> LDS
//          (XOR swizzle) -> coalesced 512B-contiguous global stores (32 lanes/row).
// All HBM touches are >=512B contiguous — fixes the 64B-scatter ~1.2 TB/s cap.
__global__ __launch_bounds__(256, 2)
void k_out_mfma(const _Float16* __restrict__ Xh,  // (512,256) fp16
                const _Float16* __restrict__ Wh,  // (NI,256) fp16 swizzled
                const float* __restrict__ bout,   // (NI)
                float* __restrict__ C)            // (512,NI)
{
    __shared__ __align__(16) _Float16 Ws[128 * 256];   // 64 KB
    float* Cs = (float*)Ws;                            // reused as (128,128) fp32

    // bijective chunked XCD swizzle: nwg = 3128 = 8*391 exactly (m204)
    const int bid = blockIdx.x;
    const int wg  = (bid & 7) * 391 + (bid >> 3);
    const int my  = wg & 3;        // M-tile 0..3 (4 blocks sharing a W panel on one XCD)
    const int ny  = wg >> 2;       // N-tile 0..781
    const int n0  = ny * 128;      // n0 % 8 == 0 -> swizzle rows align with pre-pass

    const int tid  = threadIdx.x;
    const int lane = tid & 63;
    const int w    = tid >> 6;          // wave 0..3
    const int lr   = lane & 15;
    const int lg   = lane >> 4;         // 0..3
    const int wm   = w >> 1;            // 0..1 (M half)
    const int wn   = w & 1;             // 0..1 (N half)
    const int m0w  = my * 128 + wm * 64;

    // ---- phase 1: stage W panel, 1KB-contiguous per wave-instruction ----
#pragma unroll
    for (int it = 0; it < 16; ++it) {
        const int fid = it * 256 + tid;        // 16B chunk id, 0..4095
        const int row = fid >> 5;              // 0..127
        int gr = n0 + row; if (gr >= NI) gr = NI - 1;   // clamp; masked in epilogue
        const _Float16* src = Wh + (size_t)gr * NH + (fid & 31) * 8;
        __builtin_amdgcn_global_load_lds(
            (const __attribute__((address_space(1))) void*)src,
            (__attribute__((address_space(3))) void*)(Ws + fid * 8),
            16, 0, 0);
    }
    __syncthreads();

    // ---- phase 2: MFMA from LDS (W) + L2 (X) ----
    f32x4 acc[4][4];
#pragma unroll
    for (int nf = 0; nf < 4; ++nf)
#pragma unroll
        for (int mf = 0; mf < 4; ++mf) acc[nf][mf] = (f32x4){0.f, 0.f, 0.f, 0.f};

#pragma unroll
    for (int t = 0; t < 8; ++t) {
        const int k0 = t * 32;
        f16x8 xf[4];
#pragma unroll
        for (int mf = 0; mf < 4; ++mf)
            xf[mf] = *(const f16x8*)(Xh + (size_t)(m0w + mf * 16 + lr) * NH + k0 + lg * 8);
#pragma unroll
        for (int nf = 0; nf < 4; ++nf) {
            const int rl = wn * 64 + nf * 16 + lr;              // LDS row 0..127
            const int p  = (t * 4 + lg) ^ (rl & 7);             // phys chunk (undo swizzle)
            const f16x8 wf = *(const f16x8*)(Ws + rl * NH + p * 8);
#pragma unroll
            for (int mf = 0; mf < 4; ++mf)
                acc[nf][mf] = __builtin_amdgcn_mfma_f32_16x16x32_f16(
                    wf, xf[mf], acc[nf][mf], 0, 0, 0);
        }
    }

    // ---- phase 3: epilogue via LDS transpose, 512B-contiguous stores ----
    __syncthreads();   // all Ws reads done before overwrite
#pragma unroll
    for (int nf = 0; nf < 4; ++nf) {
        const int nb_in = wn * 64 + nf * 16 + lg * 4;   // n within block tile
        const int gn = n0 + nb_in;
        const float4 bb = (gn < NI) ? *(const float4*)(bout + gn)
                                    : make_float4(0.f, 0.f, 0.f, 0.f);
        const int q = nb_in >> 2;                       // float4 chunk 0..31
#pragma unroll
        for (int mf = 0; mf < 4; ++mf) {
            const int mi = wm * 64 + mf * 16 + lr;      // row in tile; mi&7 == lr&7
            const int p  = q ^ (lr & 7);
            float4 v;
            v.x = tanh_fast(acc[nf][mf][0] + bb.x);
            v.y = tanh_fast(acc[nf][mf][1] + bb.y);
            v.z = tanh_fast(acc[nf][mf][2] + bb.z);
            v.w = tanh_fast(acc[nf][mf][3] + bb.w);
            *(float4*)(Cs + mi * 128 + p * 4) = v;
        }
    }
    __syncthreads();
#pragma unroll
    for (int it = 0; it < 16; ++it) {
        const int fid = it * 256 + tid;        // 0..4095
        const int row = fid >> 5;              // 0..127
        const int q   = fid & 31;
        const int p   = q ^ (row & 7);
        const int gn  = n0 + q * 4;
        if (gn < NI) {
            const float4 v = *(const float4*)(Cs + row * 128 + p * 4);
            *(float4*)(C + (size_t)(my * 128 + row) * NI + gn) = v;  // 512B runs/row
        }
    }
}

extern "C" void kernel_launch(void* const* d_in, const int* in_sizes, int n_in,
                              void* d_out, int out_size, void* d_ws, size_t ws_size,
                              hipStream_t stream)
{
    const int*   idx    = (const int*)  d_in[0];
    const float* hidden = (const float*)d_in[1];   // (3,512,256)
    const float* Wih0   = (const float*)d_in[2];   // (768,100000)
    const float* WihHi  = (const float*)d_in[3];   // (2,768,256)
    const float* Whh    = (const float*)d_in[4];   // (3,768,256)
    const float* bih    = (const float*)d_in[5];   // (3,768)
    const float* bhh    = (const float*)d_in[6];   // (3,768)
    const float* Wout   = (const float*)d_in[7];   // (100000,256)
    const float* bout   = (const float*)d_in[8];   // (100000)

    float* act  = (float*)d_out;                  // (512, NI)
    float* hnew = act + (size_t)NB * NI;          // (3,512,256)
    // fp32 scratch lives in the activation region; final GEMM overwrites it.
    float* hp = act;                              // (3,512,768)
    float* xp = act + 3 * NB * H3;                // (512,768)
    // d_ws: fp16 X (256 KB) + fp16 swizzled W (51.2 MB)
    _Float16* Xh = (_Float16*)d_ws;               // (512,256)
    _Float16* Wh = Xh + (size_t)NB * NH;          // (NI,256)

    const dim3 bs(256);
    const dim3 gs_hp(NB / 64, H3 / 64, 3);
    const dim3 gs_xp(NB / 64, H3 / 64, 1);

    // ---- W fp16 conversion pre-pass (independent; coalesced both sides) ----
    k_wcvt<<<dim3(NI * 32 / 256), bs, 0, stream>>>(Wout, Wh);

    // ---- all hidden-projections (depend only on input `hidden`) ----
    k_gemm_small<<<gs_hp, bs, 0, stream>>>(hidden, Whh, bhh, hp,
                                           NB, H3, NH, NB * NH, H3 * NH, H3, NB * H3);
    // ---- layer 0 (x_proj gathered inline) ----
    k_gates0<<<NB, bs, 0, stream>>>(idx, Wih0, bih, hp, hidden, hnew);
    // ---- layer 1 ----
    k_gemm_small<<<gs_xp, bs, 0, stream>>>(hnew, WihHi, bih + H3, xp,
                                           NB, H3, NH, 0, 0, 0, 0);
    k_gates<<<NB, bs, 0, stream>>>(xp, hp + NB * H3, hidden + NB * NH, hnew + NB * NH);
    // ---- layer 2 (also emits fp16 h2) ----
    k_gemm_small<<<gs_xp, bs, 0, stream>>>(hnew + NB * NH, WihHi + H3 * NH, bih + 2 * H3, xp,
                                           NB, H3, NH, 0, 0, 0, 0);
    k_gates_last<<<NB, bs, 0, stream>>>(xp, hp + 2 * NB * H3, hidden + 2 * NB * NH,
                                        hnew + 2 * NB * NH, Xh);

    // ---- output projection: 782 N-tiles x 4 M-tiles = 3128 blocks ----
    k_out_mfma<<<dim3(3128), bs, 0, stream>>>(Xh, Wh, bout, act);
}

// Round 7
// 180.863 us; speedup vs baseline: 1.5145x; 1.1049x over previous
//
#include <hip/hip_runtime.h>
#include <math.h>
#include <stdint.h>

#define NI 100000   // N_ITEMS
#define NB 512      // batch
#define NH 256      // hidden H
#define H3 768      // 3*H

typedef _Float16 f16x8 __attribute__((ext_vector_type(8)));
typedef float    f32x4 __attribute__((ext_vector_type(4)));

__device__ __forceinline__ float tanh_fast(float x) {
    x = fminf(fmaxf(x, -9.0f), 9.0f);
    const float e = __expf(2.0f * x);
    return (e - 1.0f) * __builtin_amdgcn_rcpf(e + 1.0f);
}

// ---------------- GRU gate elementwise (layer 0: gather x_proj inline) ----------------
__global__ void k_gates0(const int* __restrict__ idx,
                         const float* __restrict__ Wih0,   // (768, NI)
                         const float* __restrict__ bih0,   // (768)
                         const float* __restrict__ hp,     // (512,768)
                         const float* __restrict__ hprev,  // (512,256)
                         float* __restrict__ hnew)         // (512,256)
{
    const int b = blockIdx.x;
    const int j = threadIdx.x;          // 0..255
    const int ib = idx[b];
    const float xr = Wih0[(size_t)(j          ) * NI + ib] + bih0[j];
    const float xz = Wih0[(size_t)(j + NH     ) * NI + ib] + bih0[j + NH];
    const float xn = Wih0[(size_t)(j + 2 * NH ) * NI + ib] + bih0[j + 2 * NH];
    const float hr = hp[b * H3 + j];
    const float hz = hp[b * H3 + NH + j];
    const float hn = hp[b * H3 + 2 * NH + j];
    const float h  = hprev[b * NH + j];
    const float r = 1.0f / (1.0f + expf(-(xr + hr)));
    const float z = 1.0f / (1.0f + expf(-(xz + hz)));
    const float n = tanhf(xn + r * hn);
    hnew[b * NH + j] = (1.0f - z) * n + z * h;
}

// ---------------- GRU gate elementwise (layer 1) ----------------
__global__ void k_gates(const float* __restrict__ xp,
                        const float* __restrict__ hp,
                        const float* __restrict__ hprev,
                        float* __restrict__ hnew)
{
    const int b = blockIdx.x;
    const int j = threadIdx.x;
    const float xr = xp[b * H3 + j];
    const float xz = xp[b * H3 + NH + j];
    const float xn = xp[b * H3 + 2 * NH + j];
    const float hr = hp[b * H3 + j];
    const float hz = hp[b * H3 + NH + j];
    const float hn = hp[b * H3 + 2 * NH + j];
    const float h  = hprev[b * NH + j];
    const float r = 1.0f / (1.0f + expf(-(xr + hr)));
    const float z = 1.0f / (1.0f + expf(-(xz + hz)));
    const float n = tanhf(xn + r * hn);
    hnew[b * NH + j] = (1.0f - z) * n + z * h;
}

// ---------------- layer 2 gates: also emit fp16 copy of h2 for the MFMA GEMM --------
__global__ void k_gates_last(const float* __restrict__ xp,
                             const float* __restrict__ hp,
                             const float* __restrict__ hprev,
                             float* __restrict__ hnew,
                             _Float16* __restrict__ Xh)    // (512,256) fp16
{
    const int b = blockIdx.x;
    const int j = threadIdx.x;
    const float xr = xp[b * H3 + j];
    const float xz = xp[b * H3 + NH + j];
    const float xn = xp[b * H3 + 2 * NH + j];
    const float hr = hp[b * H3 + j];
    const float hz = hp[b * H3 + NH + j];
    const float hn = hp[b * H3 + 2 * NH + j];
    const float h  = hprev[b * NH + j];
    const float r = 1.0f / (1.0f + expf(-(xr + hr)));
    const float z = 1.0f / (1.0f + expf(-(xz + hz)));
    const float n = tanhf(xn + r * hn);
    const float v = (1.0f - z) * n + z * h;
    hnew[b * NH + j] = v;
    Xh[b * NH + j] = (_Float16)v;
}

// ---------------- small tiled fp32 GEMM:  C = A @ B.T + bias (z-batched) ----------------
__global__ __launch_bounds__(256)
void k_gemm_small(const float* __restrict__ A0,
                  const float* __restrict__ B0,
                  const float* __restrict__ bias0,
                  float* __restrict__ C0,
                  int M, int N, int K,
                  int sA, int sB, int sBias, int sC)
{
    constexpr int BM = 64, BN = 64, BK = 32;
    __shared__ float As[BK][BM];
    __shared__ float Bs[BK][BN];

    const float* A    = A0 + (size_t)blockIdx.z * sA;
    const float* Bm   = B0 + (size_t)blockIdx.z * sB;
    const float* bias = bias0 + (size_t)blockIdx.z * sBias;
    float*       C    = C0 + (size_t)blockIdx.z * sC;

    const int tid = threadIdx.x;
    const int tx  = tid & 15;
    const int ty  = tid >> 4;
    const int m0  = blockIdx.x * BM;
    const int n0  = blockIdx.y * BN;

    float acc[4][4];
#pragma unroll
    for (int i = 0; i < 4; i++)
#pragma unroll
        for (int j = 0; j < 4; j++) acc[i][j] = 0.0f;

    for (int k0 = 0; k0 < K; k0 += BK) {
#pragma unroll
        for (int f = 0; f < 2; f++) {
            const int fid = tid + f * 256;
            const int row = fid >> 3;
            const int t4  = fid & 7;
            const int mp  = row ^ ((t4 & 3) << 3);
            {
                const float4 v = *(const float4*)(A + (size_t)(m0 + row) * K + k0 + t4 * 4);
                As[t4 * 4 + 0][mp] = v.x; As[t4 * 4 + 1][mp] = v.y;
                As[t4 * 4 + 2][mp] = v.z; As[t4 * 4 + 3][mp] = v.w;
            }
            {
                const float4 v = *(const float4*)(Bm + (size_t)(n0 + row) * K + k0 + t4 * 4);
                Bs[t4 * 4 + 0][mp] = v.x; Bs[t4 * 4 + 1][mp] = v.y;
                Bs[t4 * 4 + 2][mp] = v.z; Bs[t4 * 4 + 3][mp] = v.w;
            }
        }
        __syncthreads();
#pragma unroll
        for (int kk = 0; kk < BK; kk++) {
            const int s = ((kk >> 2) & 3) << 3;
            const float4 a0 = *(const float4*)&As[kk][(ty * 4) ^ s];
            const float4 b0 = *(const float4*)&Bs[kk][(tx * 4) ^ s];
            const float av[4] = {a0.x, a0.y, a0.z, a0.w};
            const float bv[4] = {b0.x, b0.y, b0.z, b0.w};
#pragma unroll
            for (int i = 0; i < 4; i++)
#pragma unroll
                for (int j = 0; j < 4; j++)
                    acc[i][j] = fmaf(av[i], bv[j], acc[i][j]);
        }
        __syncthreads();
    }

#pragma unroll
    for (int i = 0; i < 4; i++) {
        const size_t rowoff = (size_t)(m0 + ty * 4 + i) * N;
        const int gn = n0 + tx * 4;
        const float4 bb = *(const float4*)(bias + gn);
        float4 v;
        v.x = acc[i][0] + bb.x; v.y = acc[i][1] + bb.y;
        v.z = acc[i][2] + bb.z; v.w = acc[i][3] + bb.w;
        *(float4*)(C + rowoff + gn) = v;
    }
}

// ---------------- output projection: act = tanh(x @ Wout.T + bout), fp16 MFMA ----------
// BM=512 (whole batch), BN=64 per block -> each W row fetched from HBM exactly ONCE
// (no M-tile redundancy, no fp16 pre-pass). 512 thr = 8 waves; wave w owns m-rows
// [w*64, w*64+64), all 64 n. Full K=256 W panel (64 rows x 1KB fp32 = 64 KB) staged
// via global_load_lds in 1KB-contiguous runs, source-side 16B-chunk XOR swizzle
// (linear LDS dest + swizzled src + swizzled ds_read = both-sides rule); fp32->fp16
// cvt on LDS read (R3/R4-proven). One barrier before compute; K-loop barrier-free.
// mfma(A=W-frag, B=X-frag): D col(lane&15)=m, row((lane>>4)*4+r)=n (verified layout).
// Epilogue: two 256-row passes through the same LDS -> 256B-contiguous C stores.
__global__ __launch_bounds__(512, 4)
void k_out_mfma(const _Float16* __restrict__ Xh,  // (512,256) fp16
                const float* __restrict__ W,      // (NI,256) fp32
                const float* __restrict__ bout,   // (NI)
                float* __restrict__ C)            // (512,NI)
{
    __shared__ __align__(16) float S[16384];   // 64 KB: W panel, then C half-tiles

    const int n0   = blockIdx.x * 64;          // n-tile base (1563 tiles)
    const int tid  = threadIdx.x;
    const int w    = tid >> 6;                 // wave 0..7 -> m rows [w*64, w*64+64)
    const int lane = tid & 63;
    const int lr   = lane & 15;
    const int lg   = lane >> 4;                // 0..3

    // ---- stage W panel: 64 rows x 64 16B-chunks; each wave-instr = one full 1KB row ----
#pragma unroll
    for (int it = 0; it < 8; ++it) {
        const int fid = it * 512 + tid;        // chunk id 0..4095
        const int row = fid >> 6;              // 0..63
        const int p   = fid & 63;              // physical chunk in LDS row
        int gr = n0 + row; if (gr >= NI) gr = NI - 1;      // clamp; cols masked later
        const float* src = W + (size_t)gr * NH + (size_t)(p ^ (row & 7)) * 4;
        __builtin_amdgcn_global_load_lds(
            (const __attribute__((address_space(1))) void*)src,
            (__attribute__((address_space(3))) void*)(S + fid * 4),
            16, 0, 0);
    }

    f32x4 acc[4][4];
#pragma unroll
    for (int nf = 0; nf < 4; ++nf)
#pragma unroll
        for (int mf = 0; mf < 4; ++mf) acc[nf][mf] = (f32x4){0.f, 0.f, 0.f, 0.f};

    __syncthreads();

    const _Float16* xbase = Xh + (size_t)(w * 64 + lr) * NH + lg * 8;

    // ---- K-loop: 8 steps, no barriers; W frags from LDS (cvt), X frags from L2 ----
#pragma unroll
    for (int t = 0; t < 8; ++t) {
        f16x8 xf[4];
#pragma unroll
        for (int mf = 0; mf < 4; ++mf)
            xf[mf] = *(const f16x8*)(xbase + mf * 16 * NH + t * 32);
#pragma unroll
        for (int nf = 0; nf < 4; ++nf) {
            const int rl = nf * 16 + lr;                      // W-panel row 0..63
            const int c0 = t * 8 + ((lg * 2)     ^ (rl & 7)); // phys chunk (undo swizzle)
            const int c1 = t * 8 + ((lg * 2 + 1) ^ (rl & 7));
            const f32x4 u0 = *(const f32x4*)(S + rl * 256 + c0 * 4);
            const f32x4 u1 = *(const f32x4*)(S + rl * 256 + c1 * 4);
            f16x8 h;
            h[0] = (_Float16)u0[0]; h[1] = (_Float16)u0[1];
            h[2] = (_Float16)u0[2]; h[3] = (_Float16)u0[3];
            h[4] = (_Float16)u1[0]; h[5] = (_Float16)u1[1];
            h[6] = (_Float16)u1[2]; h[7] = (_Float16)u1[3];
#pragma unroll
            for (int mf = 0; mf < 4; ++mf)
                acc[nf][mf] = __builtin_amdgcn_mfma_f32_16x16x32_f16(
                    h, xf[mf], acc[nf][mf], 0, 0, 0);
        }
    }

    // ---- epilogue: 2 passes (256 rows each) via LDS; 256B-contiguous global stores ----
#pragma unroll
    for (int pass = 0; pass < 2; ++pass) {
        __syncthreads();                       // pass 0: all k-loop LDS reads done
        if ((w >> 2) == pass) {
            const int mloc = (w & 3) * 64;
#pragma unroll
            for (int nf = 0; nf < 4; ++nf) {
                const int gn = n0 + nf * 16 + lg * 4;
                const float4 bb = (gn < NI) ? *(const float4*)(bout + gn)
                                            : make_float4(0.f, 0.f, 0.f, 0.f);
#pragma unroll
                for (int mf = 0; mf < 4; ++mf) {
                    const int mr = mloc + mf * 16 + lr;       // 0..255
                    const int p  = (nf * 4 + lg) ^ (lr & 7);  // swizzled float4 slot
                    float4 v;
                    v.x = tanh_fast(acc[nf][mf][0] + bb.x);
                    v.y = tanh_fast(acc[nf][mf][1] + bb.y);
                    v.z = tanh_fast(acc[nf][mf][2] + bb.z);
                    v.w = tanh_fast(acc[nf][mf][3] + bb.w);
                    *(float4*)(S + mr * 64 + p * 4) = v;
                }
            }
        }
        __syncthreads();
#pragma unroll
        for (int it = 0; it < 8; ++it) {
            const int fid = it * 512 + tid;    // 0..4095
            const int row = fid >> 4;          // 0..255
            const int c   = fid & 15;          // logical float4 chunk
            const int gn  = n0 + c * 4;
            if (gn < NI) {
                const f32x4 v = *(const f32x4*)(S + row * 64 + ((c ^ (row & 7)) * 4));
                *(f32x4*)(C + (size_t)(pass * 256 + row) * NI + gn) = v;
            }
        }
    }
}

extern "C" void kernel_launch(void* const* d_in, const int* in_sizes, int n_in,
                              void* d_out, int out_size, void* d_ws, size_t ws_size,
                              hipStream_t stream)
{
    const int*   idx    = (const int*)  d_in[0];
    const float* hidden = (const float*)d_in[1];   // (3,512,256)
    const float* Wih0   = (const float*)d_in[2];   // (768,100000)
    const float* WihHi  = (const float*)d_in[3];   // (2,768,256)
    const float* Whh    = (const float*)d_in[4];   // (3,768,256)
    const float* bih    = (const float*)d_in[5];   // (3,768)
    const float* bhh    = (const float*)d_in[6];   // (3,768)
    const float* Wout   = (const float*)d_in[7];   // (100000,256)
    const float* bout   = (const float*)d_in[8];   // (100000)

    float* act  = (float*)d_out;                  // (512, NI)
    float* hnew = act + (size_t)NB * NI;          // (3,512,256)
    // fp32 scratch lives in the activation region; final GEMM overwrites it.
    float* hp = act;                              // (3,512,768)
    float* xp = act + 3 * NB * H3;                // (512,768)
    // fp16 X lives in d_ws (must survive while the big GEMM writes act)
    _Float16* Xh = (_Float16*)d_ws;               // (512,256) = 256 KB

    const dim3 bs(256);
    const dim3 gs_hp(NB / 64, H3 / 64, 3);
    const dim3 gs_xp(NB / 64, H3 / 64, 1);

    // ---- all hidden-projections (depend only on input `hidden`) ----
    k_gemm_small<<<gs_hp, bs, 0, stream>>>(hidden, Whh, bhh, hp,
                                           NB, H3, NH, NB * NH, H3 * NH, H3, NB * H3);
    // ---- layer 0 (x_proj gathered inline) ----
    k_gates0<<<NB, bs, 0, stream>>>(idx, Wih0, bih, hp, hidden, hnew);
    // ---- layer 1 ----
    k_gemm_small<<<gs_xp, bs, 0, stream>>>(hnew, WihHi, bih + H3, xp,
                                           NB, H3, NH, 0, 0, 0, 0);
    k_gates<<<NB, bs, 0, stream>>>(xp, hp + NB * H3, hidden + NB * NH, hnew + NB * NH);
    // ---- layer 2 (also emits fp16 h2) ----
    k_gemm_small<<<gs_xp, bs, 0, stream>>>(hnew + NB * NH, WihHi + H3 * NH, bih + 2 * H3, xp,
                                           NB, H3, NH, 0, 0, 0, 0);
    k_gates_last<<<NB, bs, 0, stream>>>(xp, hp + 2 * NB * H3, hidden + 2 * NB * NH,
                                        hnew + 2 * NB * NH, Xh);

    // ---- output projection: 1563 n-tiles of 64, whole batch per block ----
    k_out_mfma<<<dim3((NI + 63) / 64), dim3(512), 0, stream>>>(Xh, Wout, bout, act);
}